// Round 1
// baseline (5689.782 us; speedup 1.0000x reference)
//
#include <hip/hip_runtime.h>
#include <hip/hip_bf16.h>
#include <math.h>

using bf16 = __hip_bfloat16;
typedef __attribute__((ext_vector_type(8))) short v8s;
typedef __attribute__((ext_vector_type(4))) float v4f;

// Problem constants
static constexpr int NB   = 128;     // batch
static constexpr int TT   = 31;      // T = L-1
static constexpr int VV   = 10000;   // vocab
static constexpr int DD   = 1024;
static constexpr int KP   = 10048;   // padded K (V rounded to 64)
static constexpr int NPAD = 10112;   // padded N (V rounded to 128)

__device__ __forceinline__ void g2l16(const void* g, void* l) {
  __builtin_amdgcn_global_load_lds((const __attribute__((address_space(1))) void*)g,
                                   (__attribute__((address_space(3))) void*)l, 16, 0, 0);
}
__device__ __forceinline__ float sigm(float x) { return 1.f / (1.f + expf(-x)); }

// ---------------- sort / gathers / casts ----------------
__global__ void k_sort(const int* __restrict__ caplen, const int* __restrict__ caps,
                       int* sort_i, int* dec_i, int* caps_i,
                       float* out_sort, float* out_dec, float* out_caps) {
  __shared__ int ls[NB];
  int b = threadIdx.x;
  int len = caplen[b];
  ls[b] = len;
  __syncthreads();
  int rank = 0;
  for (int j = 0; j < NB; ++j) {
    int lj = ls[j];
    rank += (lj > len) || (lj == len && j < b);
  }
  sort_i[rank] = b;
  dec_i[rank] = len - 1;
  out_sort[rank] = (float)b;
  out_dec[rank] = (float)(len - 1);
  for (int l = 0; l < 32; ++l) {
    int v = caps[b * 32 + l];
    caps_i[rank * 32 + l] = v;
    out_caps[rank * 32 + l] = (float)v;
  }
}

__global__ void k_cast(const float* __restrict__ s, bf16* __restrict__ d, int n) {
  int i = blockIdx.x * 256 + threadIdx.x;
  int stride = gridDim.x * 256;
  for (; i < n; i += stride) d[i] = __float2bfloat16(s[i]);
}

__global__ void k_cast_pre(const float* __restrict__ s, bf16* __restrict__ d) {
  int r = blockIdx.x;                       // 0..NPAD-1
  const float* src = s + (size_t)r * VV;
  bf16* dst = d + (size_t)r * KP;
  bool rv = r < VV;
  for (int c = threadIdx.x; c < KP; c += 256)
    dst[c] = __float2bfloat16((rv && c < VV) ? src[c] : 0.f);
}

__global__ void k_cast_cat(const float* __restrict__ f1, const float* __restrict__ f2,
                           bf16* __restrict__ d) {
  int r = blockIdx.x;                       // 0..NPAD-1
  bf16* dst = d + (size_t)r * 2048;
  bool rv = r < VV;
  for (int c = threadIdx.x; c < 2048; c += 256) {
    float v = 0.f;
    if (rv) v = (c < 1024) ? f1[(size_t)r * 1024 + c] : f2[(size_t)r * 1024 + c - 1024];
    dst[c] = __float2bfloat16(v);
  }
}

__global__ void k_gattrs(const float* __restrict__ attrs, const int* __restrict__ sort_i,
                         bf16* a_bf, bf16* as_bf) {
  int b = blockIdx.x;
  int sb = sort_i[b];
  for (int e = threadIdx.x; e < 1024; e += 256) {
    a_bf[b * 1024 + e]  = __float2bfloat16(attrs[b * 1024 + e]);
    as_bf[b * 1024 + e] = __float2bfloat16(attrs[sb * 1024 + e]);
  }
}

__global__ void k_gembs(const float* __restrict__ emb, const int* __restrict__ caps_i,
                        bf16* __restrict__ embs_bf) {
  int tb = blockIdx.x;            // t*128 + b
  int t = tb >> 7, b = tb & 127;
  int cap = caps_i[b * 32 + t];
  for (int e = threadIdx.x; e < 512; e += 256)
    embs_bf[(size_t)tb * 512 + e] = __float2bfloat16(emb[(size_t)cap * 512 + e]);
}

__global__ void k_mean(const bf16* __restrict__ enc_bf, bf16* __restrict__ mean_bf) {
  int b = blockIdx.x;
  int e = blockIdx.y * 256 + threadIdx.x;
  const bf16* p = enc_bf + (size_t)b * 196 * 2048 + e;
  float s = 0.f;
  for (int q = 0; q < 196; ++q) s += __bfloat162float(p[(size_t)q * 2048]);
  mean_bf[b * 2048 + e] = __float2bfloat16(s * (1.f / 196.f));
}

__global__ void k_bias(const float* bih1, const float* bhh1, float* b1c,
                       const float* bih2, const float* bhh2, float* b2c,
                       const float* bfc1, const float* bfc2, float* buc) {
  int i = blockIdx.x * 256 + threadIdx.x;
  if (i < 4096) { b1c[i] = bih1[i] + bhh1[i]; b2c[i] = bih2[i] + bhh2[i]; }
  if (i < VV) buc[i] = bfc1[i] + bfc2[i];
}

__global__ void k_zero(float* p, int n) {
  int i = blockIdx.x * 256 + threadIdx.x;
  if (i < n) p[i] = 0.f;
}

__global__ void k_padU(bf16* U) {
  int i = blockIdx.x * 256 + threadIdx.x;   // 3968*48
  if (i < 3968 * 48) {
    int r = i / 48, c = VV + i % 48;
    U[(size_t)r * KP + c] = __float2bfloat16(0.f);
  }
}

// ---------------- skinny split-K MFMA GEMM (M=128) ----------------
struct Seg {
  const bf16* A; const bf16* W; float* out;
  int lda; int ldw; int nt; int kc; int nb;
};
struct SegPack { Seg s[6]; };

__global__ __launch_bounds__(256, 2) void k_skinny(SegPack P) {
  __shared__ __align__(16) bf16 As[128 * 64];
  __shared__ __align__(16) bf16 Bs[64 * 64];
  int blk = blockIdx.x;
  int si = 0;
  while (blk >= P.s[si].nb) { blk -= P.s[si].nb; ++si; }
  const Seg s = P.s[si];
  int nblk = blk % s.nt;
  int kidx = blk / s.nt;
  int N = s.nt * 64;
  int tid = threadIdx.x, wave = tid >> 6, lane = tid & 63;
  int lr = lane & 15, lq = lane >> 4;
  int srow = lane >> 3, scol = (lane & 7) * 8;
  const bf16* Ab = s.A + kidx * 512;
  const bf16* Wb = s.W + (size_t)(nblk * 64) * s.ldw + kidx * 512;
  v4f acc[8];
#pragma unroll
  for (int i = 0; i < 8; ++i) acc[i] = (v4f){0.f, 0.f, 0.f, 0.f};
  for (int k0 = 0; k0 < 512; k0 += 64) {
#pragma unroll
    for (int c = wave; c < 16; c += 4)
      g2l16(Ab + (size_t)(c * 8 + srow) * s.lda + k0 + scol, &As[c * 512]);
#pragma unroll
    for (int c = wave; c < 8; c += 4)
      g2l16(Wb + (size_t)(c * 8 + srow) * s.ldw + k0 + scol, &Bs[c * 512]);
    __syncthreads();
#pragma unroll
    for (int kk = 0; kk < 2; ++kk) {
      int ko = kk * 32 + lq * 8;
      v8s bfrag = *(const v8s*)&Bs[(wave * 16 + lr) * 64 + ko];
#pragma unroll
      for (int i = 0; i < 8; ++i) {
        v8s afrag = *(const v8s*)&As[(i * 16 + lr) * 64 + ko];
        acc[i] = __builtin_amdgcn_mfma_f32_16x16x32_bf16(afrag, bfrag, acc[i], 0, 0, 0);
      }
    }
    __syncthreads();
  }
  float* outp = s.out + (size_t)kidx * 128 * N;
  int col = nblk * 64 + wave * 16 + lr;
#pragma unroll
  for (int i = 0; i < 8; ++i)
#pragma unroll
    for (int r = 0; r < 4; ++r)
      outp[(size_t)(i * 16 + lq * 4 + r) * N + col] = acc[i][r];
}

// ---------------- big 128x128x64 MFMA GEMM (m97 structure) ----------------
// EPI 0: bf16 store with fp32 bias (C row-major, ldc)
// EPI 1: predictions scatter: row -> (t=row>>7, b=row&127), masked-zero
template <int EPI>
__global__ __launch_bounds__(256, 2) void k_gemm128(
    const bf16* __restrict__ A, int lda, const bf16* __restrict__ Bw, int ldb,
    int K, int Nstore, const float* __restrict__ bias,
    void* __restrict__ Cout, int ldc, const int* __restrict__ dec) {
  __shared__ __align__(16) bf16 As[128 * 64];
  __shared__ __align__(16) bf16 Bs[128 * 64];
  int mblk = blockIdx.x, nblk = blockIdx.y;
  int tid = threadIdx.x, wave = tid >> 6, lane = tid & 63;
  int lr = lane & 15, lq = lane >> 4;
  int srow = lane >> 3, scol = (lane & 7) * 8;
  int wm = (wave >> 1) * 64, wn = (wave & 1) * 64;
  const bf16* Ab = A + (size_t)(mblk * 128) * lda;
  const bf16* Bb = Bw + (size_t)(nblk * 128) * ldb;
  v4f acc[4][4];
#pragma unroll
  for (int i = 0; i < 4; ++i)
#pragma unroll
    for (int j = 0; j < 4; ++j) acc[i][j] = (v4f){0.f, 0.f, 0.f, 0.f};
  for (int k0 = 0; k0 < K; k0 += 64) {
#pragma unroll
    for (int c = wave; c < 16; c += 4) {
      g2l16(Ab + (size_t)(c * 8 + srow) * lda + k0 + scol, &As[c * 512]);
      g2l16(Bb + (size_t)(c * 8 + srow) * ldb + k0 + scol, &Bs[c * 512]);
    }
    __syncthreads();
#pragma unroll
    for (int kk = 0; kk < 2; ++kk) {
      int ko = kk * 32 + lq * 8;
      v8s a[4], b[4];
#pragma unroll
      for (int i = 0; i < 4; ++i) a[i] = *(const v8s*)&As[(wm + i * 16 + lr) * 64 + ko];
#pragma unroll
      for (int j = 0; j < 4; ++j) b[j] = *(const v8s*)&Bs[(wn + j * 16 + lr) * 64 + ko];
#pragma unroll
      for (int i = 0; i < 4; ++i)
#pragma unroll
        for (int j = 0; j < 4; ++j)
          acc[i][j] = __builtin_amdgcn_mfma_f32_16x16x32_bf16(a[i], b[j], acc[i][j], 0, 0, 0);
    }
    __syncthreads();
  }
#pragma unroll
  for (int i = 0; i < 4; ++i) {
#pragma unroll
    for (int j = 0; j < 4; ++j) {
      int colg = nblk * 128 + wn + j * 16 + lr;
      if (colg < Nstore) {
        float bv = bias[colg];
#pragma unroll
        for (int r = 0; r < 4; ++r) {
          int rowg = mblk * 128 + wm + i * 16 + lq * 4 + r;
          float v = acc[i][j][r] + bv;
          if (EPI == 0) {
            ((bf16*)Cout)[(size_t)rowg * ldc + colg] = __float2bfloat16(v);
          } else {
            int t = rowg >> 7, bb = rowg & 127;
            ((float*)Cout)[(size_t)bb * (TT * VV) + (size_t)t * VV + colg] =
                (t < dec[bb]) ? v : 0.f;
          }
        }
      }
    }
  }
}

// ---------------- pointwise ----------------
__global__ void k_init_pw(const float* x0p, const float* b_x0, bf16* x0_bf,
                          const float* h10p, const float* b_h1, bf16* h10_bf,
                          const float* c1p, const float* b_c1, float* c1f,
                          const float* h20p, const float* b_h2, bf16* Hcat,
                          const float* c2p, const float* b_c2, float* c2f) {
  int idx = blockIdx.x * 256 + threadIdx.x;
  if (idx < 65536) {
    int e = idx & 511;
    x0_bf[idx] = __float2bfloat16(x0p[idx] + x0p[65536 + idx] + b_x0[e]);
    return;
  }
  idx -= 65536;
  if (idx < 131072) {
    int e = idx & 1023;
    h10_bf[idx] = __float2bfloat16(h10p[idx] + h10p[131072 + idx] + b_h1[e]);
    return;
  }
  idx -= 131072;
  if (idx < 131072) {
    int e = idx & 1023;
    c1f[idx] = c1p[idx] + c1p[131072 + idx] + b_c1[e];
    return;
  }
  idx -= 131072;
  if (idx < 131072) {
    int e = idx & 1023, b = idx >> 10;
    Hcat[b * 2048 + 1024 + e] = __float2bfloat16(
        h20p[idx] + h20p[131072 + idx] + h20p[262144 + idx] + h20p[393216 + idx] + b_h2[e]);
    return;
  }
  idx -= 131072;
  if (idx < 131072) {
    int e = idx & 1023;
    c2f[idx] = c2p[idx] + c2p[131072 + idx] + c2p[262144 + idx] + c2p[393216 + idx] + b_c2[e];
  }
}

// gp: np partials of [128,4096] (stride 524288). h_new row stride 2048 (Hcat).
__global__ void k_lstm_pw(const float* __restrict__ gp, int np, const float* __restrict__ bias,
                          float* __restrict__ c, const bf16* __restrict__ h_old, int ld_old,
                          bf16* __restrict__ h_new, const int* __restrict__ dec, int t) {
  int b = blockIdx.x;
  bool act = t < dec[b];
  for (int d = threadIdx.x; d < 1024; d += 256) {
    if (act) {
      float gi = 0, gf = 0, gg = 0, go = 0;
      for (int p = 0; p < np; ++p) {
        const float* g = gp + (size_t)p * 524288 + b * 4096;
        gi += g[d]; gf += g[1024 + d]; gg += g[2048 + d]; go += g[3072 + d];
      }
      gi += bias[d]; gf += bias[1024 + d]; gg += bias[2048 + d]; go += bias[3072 + d];
      float ci = c[b * 1024 + d];
      float cn = sigm(gf) * ci + sigm(gi) * tanhf(gg);
      float hn = sigm(go) * tanhf(cn);
      c[b * 1024 + d] = cn;
      h_new[b * 2048 + d] = __float2bfloat16(hn);
    } else {
      h_new[b * 2048 + d] = h_old[b * ld_old + d];
    }
  }
}

// attention scores + softmax -> alpha [128,196]
__global__ void k_att(const float* __restrict__ att2p, const float* __restrict__ b_da,
                      const float* __restrict__ w_fa, const float* __restrict__ b_fa,
                      const bf16* __restrict__ att1, float* __restrict__ alpha) {
  int b = blockIdx.x, tid = threadIdx.x, wave = tid >> 6, lane = tid & 63;
  __shared__ float att2s[512];
  __shared__ float sc[196];
  __shared__ float red[8];
  for (int e = tid; e < 512; e += 256)
    att2s[e] = att2p[b * 512 + e] + att2p[65536 + b * 512 + e] + b_da[e];
  __syncthreads();
  float bfa = b_fa[0];
  for (int p = wave; p < 196; p += 4) {
    const bf16* arow = att1 + ((size_t)b * 196 + p) * 512 + lane * 8;
    float s = 0.f;
#pragma unroll
    for (int j = 0; j < 8; ++j) {
      float v = __bfloat162float(arow[j]) + att2s[lane * 8 + j];
      s += fmaxf(v, 0.f) * w_fa[lane * 8 + j];
    }
    for (int off = 32; off; off >>= 1) s += __shfl_down(s, off);
    if (lane == 0) sc[p] = s + bfa;
  }
  __syncthreads();
  float v = (tid < 196) ? sc[tid] : -1e30f;
  float m = v;
  for (int off = 32; off; off >>= 1) m = fmaxf(m, __shfl_xor(m, off));
  if (lane == 0) red[wave] = m;
  __syncthreads();
  float bm = fmaxf(fmaxf(red[0], red[1]), fmaxf(red[2], red[3]));
  float e = (tid < 196) ? expf(v - bm) : 0.f;
  float ss = e;
  for (int off = 32; off; off >>= 1) ss += __shfl_xor(ss, off);
  if (lane == 0) red[4 + wave] = ss;
  __syncthreads();
  float tot = red[4] + red[5] + red[6] + red[7];
  if (tid < 196) alpha[b * 196 + tid] = e / tot;
}

// awe = gate * (alpha-weighted enc sum); also builds xcat2 = [x_t | gated awe]
__global__ void k_awe(const float* __restrict__ alpha, const bf16* __restrict__ enc_bf,
                      const float* __restrict__ gatep, const float* __restrict__ b_fb,
                      const bf16* __restrict__ xsrc, bf16* __restrict__ xcat2) {
  int b = blockIdx.x, ch = blockIdx.y, tid = threadIdx.x;
  if (ch < 8) {
    __shared__ float al[196];
    for (int p = tid; p < 196; p += 256) al[p] = alpha[b * 196 + p];
    __syncthreads();
    int e = ch * 256 + tid;
    const bf16* ebase = enc_bf + (size_t)b * 196 * 2048 + e;
    float s = 0.f;
    for (int p = 0; p < 196; ++p) s += al[p] * __bfloat162float(ebase[(size_t)p * 2048]);
    float g = gatep[b * 2048 + e] + gatep[262144 + b * 2048 + e] + b_fb[e];
    g = 1.f / (1.f + expf(-g));
    xcat2[b * 2560 + 512 + e] = __float2bfloat16(g * s);
  } else {
    int i = (ch - 8) * 256 + tid;
    xcat2[b * 2560 + i] = xsrc[b * 512 + i];
  }
}

// ---------------- host ----------------
extern "C" void kernel_launch(void* const* d_in, const int* in_sizes, int n_in,
                              void* d_out, int out_size, void* d_ws, size_t ws_size,
                              hipStream_t stream) {
  const float* attrs  = (const float*)d_in[0];
  const float* enc    = (const float*)d_in[1];
  const int*   caps   = (const int*)d_in[2];
  const int*   caplen = (const int*)d_in[3];
  const float* emb    = (const float*)d_in[4];
  const float* W_x0 = (const float*)d_in[5];  const float* b_x0 = (const float*)d_in[6];
  const float* W_h1 = (const float*)d_in[7];  const float* b_h1 = (const float*)d_in[8];
  const float* W_c1 = (const float*)d_in[9];  const float* b_c1 = (const float*)d_in[10];
  const float* W_fc1= (const float*)d_in[11]; const float* b_fc1= (const float*)d_in[12];
  const float* W_ea = (const float*)d_in[13]; const float* b_ea = (const float*)d_in[14];
  const float* W_da = (const float*)d_in[15]; const float* b_da = (const float*)d_in[16];
  const float* W_fa = (const float*)d_in[17]; const float* b_fa = (const float*)d_in[18];
  const float* W_h2 = (const float*)d_in[19]; const float* b_h2 = (const float*)d_in[20];
  const float* W_c2 = (const float*)d_in[21]; const float* b_c2 = (const float*)d_in[22];
  const float* W_fb = (const float*)d_in[23]; const float* b_fb = (const float*)d_in[24];
  const float* W_fc2= (const float*)d_in[25]; const float* b_fc2= (const float*)d_in[26];
  const float* W_pre= (const float*)d_in[27]; const float* b_pre= (const float*)d_in[28];
  const float* W_ih1= (const float*)d_in[29]; const float* b_ih1= (const float*)d_in[30];
  const float* W_hh1= (const float*)d_in[31]; const float* b_hh1= (const float*)d_in[32];
  const float* W_ih2= (const float*)d_in[33]; const float* b_ih2= (const float*)d_in[34];
  const float* W_hh2= (const float*)d_in[35]; const float* b_hh2= (const float*)d_in[36];
  (void)in_sizes; (void)n_in; (void)out_size; (void)ws_size;

  float* outp = (float*)d_out;
  const size_t OFF_PRED = 0;
  const size_t OFF_CAPS = 39680000;
  const size_t OFF_DECL = 39684096;
  const size_t OFF_ALPH = 39684224;
  const size_t OFF_SORT = 40461952;

  char* w = (char*)d_ws;
  size_t off = 0;
  auto alloc = [&](size_t bytes) -> void* {
    void* p = w + off;
    off += (bytes + 255) & ~(size_t)255;
    return p;
  };
  bf16* Wpre_bf = (bf16*)alloc((size_t)NPAD * KP * 2);
  bf16* Wfc_bf  = (bf16*)alloc((size_t)NPAD * 2048 * 2);
  bf16* U       = (bf16*)alloc((size_t)3968 * KP * 2);
  bf16* enc_bf  = (bf16*)alloc((size_t)128 * 196 * 2048 * 2);
  bf16* att1_bf = (bf16*)alloc((size_t)25088 * 512 * 2);
  bf16* embs_bf = (bf16*)alloc((size_t)3968 * 512 * 2);
  bf16* Hcat    = (bf16*)alloc((size_t)4224 * 2048 * 2);
  bf16* Wih1_bf = (bf16*)alloc((size_t)4096 * 512 * 2);
  bf16* Whh1_bf = (bf16*)alloc((size_t)4096 * 1024 * 2);
  bf16* Wda_bf  = (bf16*)alloc((size_t)512 * 1024 * 2);
  bf16* Wfb_bf  = (bf16*)alloc((size_t)2048 * 1024 * 2);
  bf16* Wih2_bf = (bf16*)alloc((size_t)4096 * 2560 * 2);
  bf16* Whh2_bf = (bf16*)alloc((size_t)4096 * 1024 * 2);
  bf16* Wx0_bf  = (bf16*)alloc((size_t)512 * 1024 * 2);
  bf16* Wh1_bf  = (bf16*)alloc((size_t)1024 * 1024 * 2);
  bf16* Wc1_bf  = (bf16*)alloc((size_t)1024 * 1024 * 2);
  bf16* Wh2_bf  = (bf16*)alloc((size_t)1024 * 2048 * 2);
  bf16* Wc2_bf  = (bf16*)alloc((size_t)1024 * 2048 * 2);
  bf16* Wea_bf  = (bf16*)alloc((size_t)512 * 2048 * 2);
  float* g1p    = (float*)alloc((size_t)3 * 524288 * 4);
  float* g2p    = (float*)alloc((size_t)7 * 524288 * 4);
  float* att2p  = (float*)alloc((size_t)2 * 65536 * 4);
  float* gatep  = (float*)alloc((size_t)2 * 262144 * 4);
  float* x0p    = (float*)alloc((size_t)2 * 65536 * 4);
  float* h10p   = (float*)alloc((size_t)2 * 131072 * 4);
  float* c1p    = (float*)alloc((size_t)2 * 131072 * 4);
  float* h20p   = (float*)alloc((size_t)4 * 131072 * 4);
  float* c2p    = (float*)alloc((size_t)4 * 131072 * 4);
  float* c1f    = (float*)alloc((size_t)131072 * 4);
  float* c2f    = (float*)alloc((size_t)131072 * 4);
  bf16* x0_bf   = (bf16*)alloc((size_t)65536 * 2);
  bf16* h10_bf  = (bf16*)alloc((size_t)131072 * 2);
  bf16* mean_bf = (bf16*)alloc((size_t)262144 * 2);
  bf16* attrs_bf   = (bf16*)alloc((size_t)131072 * 2);
  bf16* attrs_s_bf = (bf16*)alloc((size_t)131072 * 2);
  bf16* xcat2   = (bf16*)alloc((size_t)327680 * 2);
  float* alpha  = (float*)alloc((size_t)25088 * 4);
  float* b1c    = (float*)alloc((size_t)4096 * 4);
  float* b2c    = (float*)alloc((size_t)4096 * 4);
  float* buc    = (float*)alloc((size_t)10016 * 4);
  int* sort_i   = (int*)alloc(128 * 4);
  int* dec_i    = (int*)alloc(128 * 4);
  int* caps_i   = (int*)alloc(4096 * 4);

  // ---- setup ----
  k_sort<<<1, 128, 0, stream>>>(caplen, caps, sort_i, dec_i, caps_i,
                                outp + OFF_SORT, outp + OFF_DECL, outp + OFF_CAPS);
  auto cast = [&](const float* s, bf16* d, int n) {
    int grid = (n + 255) / 256;
    if (grid > 4096) grid = 4096;
    k_cast<<<grid, 256, 0, stream>>>(s, d, n);
  };
  cast(enc, enc_bf, 128 * 196 * 2048);
  cast(W_ih1, Wih1_bf, 4096 * 512);
  cast(W_hh1, Whh1_bf, 4096 * 1024);
  cast(W_da, Wda_bf, 512 * 1024);
  cast(W_fb, Wfb_bf, 2048 * 1024);
  cast(W_ih2, Wih2_bf, 4096 * 2560);
  cast(W_hh2, Whh2_bf, 4096 * 1024);
  cast(W_x0, Wx0_bf, 512 * 1024);
  cast(W_h1, Wh1_bf, 1024 * 1024);
  cast(W_c1, Wc1_bf, 1024 * 1024);
  cast(W_h2, Wh2_bf, 1024 * 2048);
  cast(W_c2, Wc2_bf, 1024 * 2048);
  cast(W_ea, Wea_bf, 512 * 2048);
  k_cast_pre<<<NPAD, 256, 0, stream>>>(W_pre, Wpre_bf);
  k_cast_cat<<<NPAD, 256, 0, stream>>>(W_fc1, W_fc2, Wfc_bf);
  k_gattrs<<<128, 256, 0, stream>>>(attrs, sort_i, attrs_bf, attrs_s_bf);
  k_gembs<<<3968, 256, 0, stream>>>(emb, caps_i, embs_bf);
  k_mean<<<dim3(128, 8), 256, 0, stream>>>(enc_bf, mean_bf);
  k_bias<<<40, 256, 0, stream>>>(b_ih1, b_hh1, b1c, b_ih2, b_hh2, b2c, b_fc1, b_fc2, buc);

  SegPack P;
  int nseg = 0, nb = 0;
  auto rst = [&]() { nseg = 0; nb = 0; };
  auto seg = [&](const bf16* A_, int lda_, const bf16* W_, int ldw_, float* o_, int nt_, int kc_) {
    P.s[nseg++] = Seg{A_, W_, o_, lda_, ldw_, nt_, kc_, nt_ * kc_};
    nb += nt_ * kc_;
  };

  // init linear layers
  rst();
  seg(attrs_bf, 1024, Wx0_bf, 1024, x0p, 8, 2);
  seg(attrs_s_bf, 1024, Wh1_bf, 1024, h10p, 16, 2);
  seg(attrs_s_bf, 1024, Wc1_bf, 1024, c1p, 16, 2);
  seg(mean_bf, 2048, Wh2_bf, 2048, h20p, 16, 4);
  seg(mean_bf, 2048, Wc2_bf, 2048, c2p, 16, 4);
  k_skinny<<<nb, 256, 0, stream>>>(P);
  k_init_pw<<<2304, 256, 0, stream>>>(x0p, b_x0, x0_bf, h10p, b_h1, h10_bf,
                                      c1p, b_c1, c1f, h20p, b_h2, Hcat, c2p, b_c2, c2f);
  // initial LSTM1 (pre-scan), all batches active (t=-1)
  rst();
  seg(x0_bf, 512, Wih1_bf, 512, g1p, 64, 1);
  seg(h10_bf, 1024, Whh1_bf, 1024, g1p + 524288, 64, 2);
  k_skinny<<<nb, 256, 0, stream>>>(P);
  k_lstm_pw<<<128, 256, 0, stream>>>(g1p, 3, b1c, c1f, h10_bf, 1024, Hcat, dec_i, -1);
  // att1 = enc @ W_ea.T + b_ea  (bf16)
  k_gemm128<0><<<dim3(196, 4), 256, 0, stream>>>(enc_bf, 2048, Wea_bf, 2048, 2048, 512,
                                                 b_ea, att1_bf, 512, (const int*)nullptr);

  // ---- time loop ----
  for (int t = 0; t < TT; ++t) {
    bf16* Ht  = Hcat + (size_t)t * 262144;
    bf16* Ht1 = Hcat + (size_t)(t + 1) * 262144;
    const bf16* xt = embs_bf + (size_t)t * 65536;
    rst();
    seg(xt, 512, Wih1_bf, 512, g1p, 64, 1);
    seg(Ht, 2048, Whh1_bf, 1024, g1p + 524288, 64, 2);
    seg(Ht + 1024, 2048, Wda_bf, 1024, att2p, 8, 2);
    seg(Ht + 1024, 2048, Wfb_bf, 1024, gatep, 32, 2);
    k_skinny<<<nb, 256, 0, stream>>>(P);
    k_lstm_pw<<<128, 256, 0, stream>>>(g1p, 3, b1c, c1f, Ht, 2048, Ht1, dec_i, t);
    k_att<<<128, 256, 0, stream>>>(att2p, b_da, W_fa, b_fa, att1_bf, alpha);
    k_awe<<<dim3(128, 10), 256, 0, stream>>>(alpha, enc_bf, gatep, b_fb, xt, xcat2);
    rst();
    seg(xcat2, 2560, Wih2_bf, 2560, g2p, 64, 5);
    seg(Ht + 1024, 2048, Whh2_bf, 1024, g2p + 5 * 524288, 64, 2);
    k_skinny<<<nb, 256, 0, stream>>>(P);
    k_lstm_pw<<<128, 256, 0, stream>>>(g2p, 7, b2c, c2f, Ht + 1024, 2048, Ht1 + 1024, dec_i, t);
  }

  // ---- batched prediction GEMMs ----
  k_padU<<<(3968 * 48 + 255) / 256, 256, 0, stream>>>(U);
  k_gemm128<0><<<dim3(31, 79), 256, 0, stream>>>(Hcat + 262144, 2048, Wfc_bf, 2048, 2048,
                                                 VV, buc, U, KP, (const int*)nullptr);
  k_gemm128<1><<<dim3(31, 79), 256, 0, stream>>>(U, KP, Wpre_bf, KP, KP, VV, b_pre,
                                                 outp + OFF_PRED, 0, dec_i);
  k_zero<<<(777728 + 255) / 256, 256, 0, stream>>>(outp + OFF_ALPH, 777728);
}